// Round 1
// baseline (66.430 us; speedup 1.0000x reference)
//
#include <hip/hip_runtime.h>

typedef short v8s __attribute__((ext_vector_type(8)));
typedef float v4f __attribute__((ext_vector_type(4)));

#define NPT 100
#define IN_DIM 128
#define EMB 64

__device__ __forceinline__ unsigned short f2bf(float x) {
    unsigned int u = __float_as_uint(x);
    u += 0x7fffu + ((u >> 16) & 1u);
    return (unsigned short)(u >> 16);
}
__device__ __forceinline__ float bf2f(unsigned short h) {
    return __uint_as_float(((unsigned int)h) << 16);
}

// Pre-swizzle W_fc (fp32 [64][128]) into bf16 hi/lo MFMA B-fragments.
// Fragment (kstep, ntile): lane l holds B[k0+j][col], col=ntile*16+(l&15),
// k0=kstep*32+8*(l>>4), j=0..7.  Slot s = kstep*256 + ntile*64 + lane.
__global__ void prep_wfc(const float* __restrict__ W_fc, unsigned short* __restrict__ ws) {
    int tid = blockIdx.x * blockDim.x + threadIdx.x;
    if (tid >= 1024) return;
    int kstep = tid >> 8;
    int ntile = (tid >> 6) & 3;
    int lane  = tid & 63;
    int emb = ntile * 16 + (lane & 15);
    int k0  = kstep * 32 + 8 * (lane >> 4);
    const float* src = W_fc + emb * IN_DIM + k0;
    #pragma unroll
    for (int j = 0; j < 8; ++j) {
        float x = src[j];
        unsigned short hi = f2bf(x);
        unsigned short lo = f2bf(x - bf2f(hi));
        ws[tid * 8 + j] = hi;
        ws[8192 + tid * 8 + j] = lo;
    }
}

// One block (256 threads, 4 waves) per team: fused FC + 2-level GAT + readout.
__global__ __launch_bounds__(256, 4) void team_kernel(
    const float* __restrict__ f, const float* __restrict__ salary,
    const float* __restrict__ W_attn, const float* __restrict__ b_attn,
    const float* __restrict__ W_out, const float* __restrict__ b_out,
    const unsigned short* __restrict__ wfrag, float* __restrict__ out)
{
    __shared__ float z_lds[NPT][66];   // pitch 66: (66n+k)%32 -> <=2-way (free)
    __shared__ float attn_lds[128];    // a_l = [0:64), a_r = [64:128)
    __shared__ float wout_lds[130];    // W_out flat [2][65]
    __shared__ float sL[4];            // a_l . z  for nodes 0..3 (hc, c0..c2)
    __shared__ float sR[96];           // a_r . z  for positions (nodes 4..99)
    __shared__ float alpha1[96];
    __shared__ float sRn[3];           // a_r . z_new for coords

    const int tid  = threadIdx.x;
    const int lane = tid & 63;
    const int wave = tid >> 6;
    const int team = blockIdx.x;

    if (tid < 128) attn_lds[tid] = W_attn[tid];
    if (tid < 130) wout_lds[tid] = W_out[tid];
    const float bA = b_attn[0];

    // ---------- FC: z = relu(f_team @ W_fc^T), bf16 hi/lo split MFMA ----------
    const float* fteam = f + (size_t)team * (NPT * IN_DIM);
    const v4f vzero = {0.f, 0.f, 0.f, 0.f};
    v4f acc[2][4];
    #pragma unroll
    for (int m = 0; m < 2; ++m)
        #pragma unroll
        for (int n = 0; n < 4; ++n) acc[m][n] = vzero;

    const int row0 = wave * 32;   // wave owns rows [row0, row0+32)
    #pragma unroll
    for (int kstep = 0; kstep < 4; ++kstep) {
        const int k0 = kstep * 32 + 8 * (lane >> 4);
        v8s a_hi[2], a_lo[2];
        #pragma unroll
        for (int m = 0; m < 2; ++m) {
            int row = row0 + m * 16 + (lane & 15);
            if (row > NPT - 1) row = NPT - 1;      // clamp; results discarded
            const float* src = fteam + row * IN_DIM + k0;
            float4 x0 = *(const float4*)(src);
            float4 x1 = *(const float4*)(src + 4);
            float xs[8] = {x0.x, x0.y, x0.z, x0.w, x1.x, x1.y, x1.z, x1.w};
            #pragma unroll
            for (int j = 0; j < 8; ++j) {
                unsigned short h = f2bf(xs[j]);
                a_hi[m][j] = (short)h;
                a_lo[m][j] = (short)f2bf(xs[j] - bf2f(h));
            }
        }
        #pragma unroll
        for (int n = 0; n < 4; ++n) {
            const int s = kstep * 256 + n * 64 + lane;
            v8s b_hi = *(const v8s*)(wfrag + s * 8);
            v8s b_lo = *(const v8s*)(wfrag + 8192 + s * 8);
            #pragma unroll
            for (int m = 0; m < 2; ++m) {
                acc[m][n] = __builtin_amdgcn_mfma_f32_16x16x32_bf16(a_hi[m], b_hi, acc[m][n], 0, 0, 0);
                acc[m][n] = __builtin_amdgcn_mfma_f32_16x16x32_bf16(a_hi[m], b_lo, acc[m][n], 0, 0, 0);
                acc[m][n] = __builtin_amdgcn_mfma_f32_16x16x32_bf16(a_lo[m], b_hi, acc[m][n], 0, 0, 0);
            }
        }
    }
    // C/D layout (m89-verified): col = lane&15, row = 4*(lane>>4)+j
    #pragma unroll
    for (int m = 0; m < 2; ++m) {
        const int rbase = row0 + m * 16 + 4 * (lane >> 4);
        #pragma unroll
        for (int n = 0; n < 4; ++n) {
            const int col = n * 16 + (lane & 15);
            #pragma unroll
            for (int j = 0; j < 4; ++j) {
                const int r = rbase + j;
                if (r < NPT) z_lds[r][col] = fmaxf(acc[m][n][j], 0.f);
            }
        }
    }
    __syncthreads();

    // ---------- attention projections on original z ----------
    if (tid < 100) {
        float s = 0.f;
        if (tid < 96) {                       // positions: need a_r . z
            const int node = 4 + tid;
            #pragma unroll 8
            for (int k = 0; k < EMB; ++k) s += attn_lds[64 + k] * z_lds[node][k];
            sR[tid] = s;
        } else {                              // hc + coords: need a_l . z
            const int node = tid - 96;
            #pragma unroll 8
            for (int k = 0; k < EMB; ++k) s += attn_lds[k] * z_lds[node][k];
            sL[node] = s;
        }
    }
    __syncthreads();

    // ---------- level 1: coord <- its 32 positions ----------
    if (wave < 3 && lane < 32) {
        const int c = wave, p = lane;
        float e = sL[1 + c] + sR[c * 32 + p] + bA;
        e = e > 0.f ? e : 0.01f * e;          // leaky_relu slope 0.01
        float mx = e;
        #pragma unroll
        for (int off = 16; off >= 1; off >>= 1) mx = fmaxf(mx, __shfl_xor(mx, off, 64));
        const float ex = __expf(e - mx);
        float sm = ex;
        #pragma unroll
        for (int off = 16; off >= 1; off >>= 1) sm += __shfl_xor(sm, off, 64);
        alpha1[c * 32 + p] = ex / sm;
    }
    __syncthreads();

    // aggregate into new coord z; also a_r . z_new via full-wave reduce
    if (tid < 192) {
        const int c = tid >> 6, k = tid & 63;
        float agg = 0.f;
        #pragma unroll 8
        for (int p = 0; p < 32; ++p) agg += alpha1[c * 32 + p] * z_lds[4 + c * 32 + p][k];
        const float zn = fmaxf(agg, 0.f);
        z_lds[1 + c][k] = zn;                 // rows 1..3 no longer needed as-old
        float pr = attn_lds[64 + k] * zn;
        #pragma unroll
        for (int off = 32; off >= 1; off >>= 1) pr += __shfl_xor(pr, off, 64);
        if (k == 0) sRn[c] = pr;
    }
    __syncthreads();

    // ---------- level 2 (hc <- coords) + readout, wave 0 ----------
    if (wave == 0) {
        const int k = lane;
        float e0 = sL[0] + sRn[0] + bA; e0 = e0 > 0.f ? e0 : 0.01f * e0;
        float e1 = sL[0] + sRn[1] + bA; e1 = e1 > 0.f ? e1 : 0.01f * e1;
        float e2 = sL[0] + sRn[2] + bA; e2 = e2 > 0.f ? e2 : 0.01f * e2;
        const float mx = fmaxf(e0, fmaxf(e1, e2));
        const float x0 = __expf(e0 - mx), x1 = __expf(e1 - mx), x2 = __expf(e2 - mx);
        const float inv = 1.f / (x0 + x1 + x2);
        const float zh = fmaxf(
            (x0 * inv) * z_lds[1][k] + (x1 * inv) * z_lds[2][k] + (x2 * inv) * z_lds[3][k],
            0.f);
        float p0 = wout_lds[k]      * zh;
        float p1 = wout_lds[65 + k] * zh;
        #pragma unroll
        for (int off = 32; off >= 1; off >>= 1) {
            p0 += __shfl_xor(p0, off, 64);
            p1 += __shfl_xor(p1, off, 64);
        }
        if (lane == 0) {
            const float sal = salary[team];
            float y0 = fmaxf(p0 + wout_lds[64]  * sal + b_out[0], 0.f);
            float y1 = fmaxf(p1 + wout_lds[129] * sal + b_out[1], 0.f);
            const float mm = fmaxf(y0, y1);
            const float q0 = __expf(y0 - mm), q1 = __expf(y1 - mm);
            const float is = 1.f / (q0 + q1);
            out[team * 2 + 0] = q0 * is;
            out[team * 2 + 1] = q1 * is;
        }
    }
}

extern "C" void kernel_launch(void* const* d_in, const int* in_sizes, int n_in,
                              void* d_out, int out_size, void* d_ws, size_t ws_size,
                              hipStream_t stream) {
    const float* f      = (const float*)d_in[0];
    const float* salary = (const float*)d_in[1];
    const float* W_fc   = (const float*)d_in[2];
    const float* W_attn = (const float*)d_in[3];
    const float* b_attn = (const float*)d_in[4];
    const float* W_out  = (const float*)d_in[5];
    const float* b_out  = (const float*)d_in[6];
    // d_in[7..11] (src1, tgt1, src2, tgt2, hc_ids) are deterministic structure; unused.
    unsigned short* wfrag = (unsigned short*)d_ws;   // 32 KB: hi[8192] + lo[8192] shorts

    prep_wfc<<<dim3(4), dim3(256), 0, stream>>>(W_fc, wfrag);
    team_kernel<<<dim3(4096), dim3(256), 0, stream>>>(
        f, salary, W_attn, b_attn, W_out, b_out, wfrag, (float*)d_out);
}

// Round 3
// 59.273 us; speedup vs baseline: 1.1207x; 1.1207x over previous
//
#include <hip/hip_runtime.h>

typedef short v8s __attribute__((ext_vector_type(8)));
typedef float v4f __attribute__((ext_vector_type(4)));

#define NPT 100
#define IN_DIM 128
#define EMB 64

__device__ __forceinline__ unsigned short f2bf(float x) {
    unsigned int u = __float_as_uint(x);
    u += 0x7fffu + ((u >> 16) & 1u);
    return (unsigned short)(u >> 16);
}
__device__ __forceinline__ float bf2f(unsigned short h) {
    return __uint_as_float(((unsigned int)h) << 16);
}

// Pre-swizzle W_fc (fp32 [64][128]) into bf16 hi/lo MFMA B-fragments.
// Fragment (kstep, ntile): lane l holds B[k0+j][col], col=ntile*16+(l&15),
// k0=kstep*32+8*(l>>4), j=0..7.  Slot s = kstep*256 + ntile*64 + lane.
// Layout in ws: hi at shorts [0, 8192), lo at [8192, 16384)  (32 KB total).
__global__ void prep_wfc(const float* __restrict__ W_fc, unsigned short* __restrict__ ws) {
    int tid = blockIdx.x * blockDim.x + threadIdx.x;
    if (tid >= 1024) return;
    int kstep = tid >> 8;
    int ntile = (tid >> 6) & 3;
    int lane  = tid & 63;
    int emb = ntile * 16 + (lane & 15);
    int k0  = kstep * 32 + 8 * (lane >> 4);
    const float* src = W_fc + emb * IN_DIM + k0;
    #pragma unroll
    for (int j = 0; j < 8; ++j) {
        float x = src[j];
        unsigned short hi = f2bf(x);
        unsigned short lo = f2bf(x - bf2f(hi));
        ws[tid * 8 + j] = hi;
        ws[8192 + tid * 8 + j] = lo;
    }
}

// Packed bf16 convert: D = {bf16(x0) | bf16(x1)<<16}, RNE.  No builtin on
// gfx950 (guide T12) -> inline asm.
__device__ __forceinline__ unsigned int cvt_pk(float x0, float x1) {
    unsigned int r;
    asm("v_cvt_pk_bf16_f32 %0, %1, %2" : "=v"(r) : "v"(x0), "v"(x1));
    return r;
}

// Split x0,x1 into rounded bf16 hi + bf16(residual) lo, both packed as u32.
__device__ __forceinline__ void cvt2(float x0, float x1, unsigned int& hi, unsigned int& lo) {
    unsigned int h = cvt_pk(x0, x1);
    float h0 = __uint_as_float(h << 16);
    float h1 = __uint_as_float(h & 0xffff0000u);
    lo = cvt_pk(x0 - h0, x1 - h1);
    hi = h;
}

union ABfrag { v8s v; unsigned int u[4]; };

// One block (256 threads, 4 waves) per team: fused FC + 2-level GAT + readout.
__global__ __launch_bounds__(256, 4) void team_kernel(
    const float* __restrict__ f, const float* __restrict__ salary,
    const float* __restrict__ W_attn, const float* __restrict__ b_attn,
    const float* __restrict__ W_out, const float* __restrict__ b_out,
    const unsigned short* __restrict__ wfrag, float* __restrict__ out)
{
    // smem is time-shared: phase 1 = W fragments (32 KB), phase 2 = z[100][66] (26.4 KB)
    __shared__ __align__(16) char smem[32768];
    __shared__ float attn_lds[128];    // a_l = [0:64), a_r = [64:128)
    __shared__ float wout_lds[130];    // W_out flat [2][65]
    __shared__ float sL[4];            // a_l . z  for nodes 0..3 (hc, c0..c2)
    __shared__ float sR[96];           // a_r . z  for positions (nodes 4..99)
    __shared__ float alpha1[96];
    __shared__ float sRn[3];           // a_r . z_new for coords

    const int tid  = threadIdx.x;
    const int lane = tid & 63;
    const int wave = tid >> 6;
    const int team = blockIdx.x;

    unsigned short* wl = (unsigned short*)smem;
    float (*z_lds)[66] = (float (*)[66])smem;   // pitch 66: <=2-way bank alias (free)

    // ---- stage W fragments (32 KB) into LDS: 8 x (4 waves x 1 KB), DMA ----
    #pragma unroll
    for (int i = 0; i < 8; ++i) {
        const unsigned int off = i * 4096 + wave * 1024;       // wave-uniform dest
        __builtin_amdgcn_global_load_lds(
            (const __attribute__((address_space(1))) unsigned int*)((const char*)wfrag + off + lane * 16),
            (__attribute__((address_space(3))) unsigned int*)(smem + off), 16, 0, 0);
    }

    if (tid < 128) attn_lds[tid] = W_attn[tid];
    if (tid < 130) wout_lds[tid] = W_out[tid];
    const float bA = b_attn[0];

    // ---- load + convert ALL A fragments before the barrier (hide stage DMA) ----
    // tile t = 2*wave + m covers rows [16t, 16t+16); tile 7 is dead (only 100 rows).
    const float* fteam = f + (size_t)team * (NPT * IN_DIM);
    ABfrag ah[4][2], al[4][2];
    #pragma unroll
    for (int kstep = 0; kstep < 4; ++kstep) {
        const int k0 = kstep * 32 + 8 * (lane >> 4);
        #pragma unroll
        for (int m = 0; m < 2; ++m) {
            if (m == 1 && wave == 3) continue;                 // dead tile 7
            int row = 32 * wave + m * 16 + (lane & 15);
            if (row > NPT - 1) row = NPT - 1;                  // clamp; results discarded
            const float* src = fteam + row * IN_DIM + k0;
            float4 x0 = *(const float4*)(src);
            float4 x1 = *(const float4*)(src + 4);
            cvt2(x0.x, x0.y, ah[kstep][m].u[0], al[kstep][m].u[0]);
            cvt2(x0.z, x0.w, ah[kstep][m].u[1], al[kstep][m].u[1]);
            cvt2(x1.x, x1.y, ah[kstep][m].u[2], al[kstep][m].u[2]);
            cvt2(x1.z, x1.w, ah[kstep][m].u[3], al[kstep][m].u[3]);
        }
    }

    const v4f vzero = {0.f, 0.f, 0.f, 0.f};
    v4f acc[2][4];
    #pragma unroll
    for (int m = 0; m < 2; ++m)
        #pragma unroll
        for (int n = 0; n < 4; ++n) acc[m][n] = vzero;

    __syncthreads();   // W staged; A converted in regs

    // ---- MFMA: B from LDS (ds_read_b128), 3-term hi/lo product ----
    #pragma unroll
    for (int kstep = 0; kstep < 4; ++kstep) {
        #pragma unroll
        for (int n = 0; n < 4; ++n) {
            const int s = kstep * 256 + n * 64 + lane;
            v8s bh = *(const v8s*)(wl + s * 8);
            v8s bl = *(const v8s*)(wl + 8192 + s * 8);
            #pragma unroll
            for (int m = 0; m < 2; ++m) {
                if (m == 1 && wave == 3) continue;
                acc[m][n] = __builtin_amdgcn_mfma_f32_16x16x32_bf16(ah[kstep][m].v, bh, acc[m][n], 0, 0, 0);
                acc[m][n] = __builtin_amdgcn_mfma_f32_16x16x32_bf16(ah[kstep][m].v, bl, acc[m][n], 0, 0, 0);
                acc[m][n] = __builtin_amdgcn_mfma_f32_16x16x32_bf16(al[kstep][m].v, bh, acc[m][n], 0, 0, 0);
            }
        }
    }

    __syncthreads();   // all W ds_reads done before smem is reused for z

    // C/D layout (m89-verified): col = lane&15, row = 4*(lane>>4)+j
    #pragma unroll
    for (int m = 0; m < 2; ++m) {
        if (m == 1 && wave == 3) continue;
        const int rbase = 32 * wave + m * 16 + 4 * (lane >> 4);
        #pragma unroll
        for (int n = 0; n < 4; ++n) {
            const int col = n * 16 + (lane & 15);
            #pragma unroll
            for (int j = 0; j < 4; ++j) {
                const int r = rbase + j;
                if (r < NPT) z_lds[r][col] = fmaxf(acc[m][n][j], 0.f);
            }
        }
    }
    __syncthreads();

    // ---------- attention projections on original z (4-acc pipelined dots) ----------
    if (tid < 100) {
        const int isPos = (tid < 96);
        const int node = isPos ? (4 + tid) : (tid - 96);
        const float* av = attn_lds + (isPos ? 64 : 0);
        const float* zr = z_lds[node];
        float s0 = 0.f, s1 = 0.f, s2 = 0.f, s3 = 0.f;
        #pragma unroll
        for (int k = 0; k < EMB; k += 4) {
            s0 += av[k]     * zr[k];
            s1 += av[k + 1] * zr[k + 1];
            s2 += av[k + 2] * zr[k + 2];
            s3 += av[k + 3] * zr[k + 3];
        }
        const float s = (s0 + s1) + (s2 + s3);
        if (isPos) sR[tid] = s; else sL[node] = s;
    }
    __syncthreads();

    // ---------- level 1: coord <- its 32 positions ----------
    if (wave < 3 && lane < 32) {
        const int c = wave, p = lane;
        float e = sL[1 + c] + sR[c * 32 + p] + bA;
        e = e > 0.f ? e : 0.01f * e;          // leaky_relu slope 0.01
        float mx = e;
        #pragma unroll
        for (int off = 16; off >= 1; off >>= 1) mx = fmaxf(mx, __shfl_xor(mx, off, 64));
        const float ex = __expf(e - mx);
        float sm = ex;
        #pragma unroll
        for (int off = 16; off >= 1; off >>= 1) sm += __shfl_xor(sm, off, 64);
        alpha1[c * 32 + p] = ex / sm;
    }
    __syncthreads();

    // aggregate into new coord z; also a_r . z_new via full-wave reduce
    if (tid < 192) {
        const int c = tid >> 6, k = tid & 63;
        float a0 = 0.f, a1 = 0.f, a2 = 0.f, a3 = 0.f;
        #pragma unroll
        for (int p = 0; p < 32; p += 4) {
            a0 += alpha1[c * 32 + p]     * z_lds[4 + c * 32 + p][k];
            a1 += alpha1[c * 32 + p + 1] * z_lds[4 + c * 32 + p + 1][k];
            a2 += alpha1[c * 32 + p + 2] * z_lds[4 + c * 32 + p + 2][k];
            a3 += alpha1[c * 32 + p + 3] * z_lds[4 + c * 32 + p + 3][k];
        }
        const float zn = fmaxf((a0 + a1) + (a2 + a3), 0.f);
        z_lds[1 + c][k] = zn;                 // rows 1..3 become new coord z
        float pr = attn_lds[64 + k] * zn;
        #pragma unroll
        for (int off = 32; off >= 1; off >>= 1) pr += __shfl_xor(pr, off, 64);
        if (k == 0) sRn[c] = pr;
    }
    __syncthreads();

    // ---------- level 2 (hc <- coords) + readout, wave 0 ----------
    if (wave == 0) {
        const int k = lane;
        float e0 = sL[0] + sRn[0] + bA; e0 = e0 > 0.f ? e0 : 0.01f * e0;
        float e1 = sL[0] + sRn[1] + bA; e1 = e1 > 0.f ? e1 : 0.01f * e1;
        float e2 = sL[0] + sRn[2] + bA; e2 = e2 > 0.f ? e2 : 0.01f * e2;
        const float mx = fmaxf(e0, fmaxf(e1, e2));
        const float x0 = __expf(e0 - mx), x1 = __expf(e1 - mx), x2 = __expf(e2 - mx);
        const float inv = 1.f / (x0 + x1 + x2);
        const float zh = fmaxf(
            (x0 * inv) * z_lds[1][k] + (x1 * inv) * z_lds[2][k] + (x2 * inv) * z_lds[3][k],
            0.f);
        float p0 = wout_lds[k]      * zh;
        float p1 = wout_lds[65 + k] * zh;
        #pragma unroll
        for (int off = 32; off >= 1; off >>= 1) {
            p0 += __shfl_xor(p0, off, 64);
            p1 += __shfl_xor(p1, off, 64);
        }
        if (lane == 0) {
            const float sal = salary[team];
            float y0 = fmaxf(p0 + wout_lds[64]  * sal + b_out[0], 0.f);
            float y1 = fmaxf(p1 + wout_lds[129] * sal + b_out[1], 0.f);
            const float mm = fmaxf(y0, y1);
            const float q0 = __expf(y0 - mm), q1 = __expf(y1 - mm);
            const float is = 1.f / (q0 + q1);
            out[team * 2 + 0] = q0 * is;
            out[team * 2 + 1] = q1 * is;
        }
    }
}

extern "C" void kernel_launch(void* const* d_in, const int* in_sizes, int n_in,
                              void* d_out, int out_size, void* d_ws, size_t ws_size,
                              hipStream_t stream) {
    const float* f      = (const float*)d_in[0];
    const float* salary = (const float*)d_in[1];
    const float* W_fc   = (const float*)d_in[2];
    const float* W_attn = (const float*)d_in[3];
    const float* b_attn = (const float*)d_in[4];
    const float* W_out  = (const float*)d_in[5];
    const float* b_out  = (const float*)d_in[6];
    // d_in[7..11] (src1, tgt1, src2, tgt2, hc_ids) are deterministic structure; unused.
    unsigned short* wfrag = (unsigned short*)d_ws;   // 32 KB: hi[8192] + lo[8192] shorts

    prep_wfc<<<dim3(4), dim3(256), 0, stream>>>(W_fc, wfrag);
    team_kernel<<<dim3(4096), dim3(256), 0, stream>>>(
        f, salary, W_attn, b_attn, W_out, b_out, wfrag, (float*)d_out);
}